// Round 16
// baseline (334.484 us; speedup 1.0000x reference)
//
#include <hip/hip_runtime.h>
#include <hip/hip_bf16.h>
#include <math.h>

// Problem constants
#define IN_DIM   384
#define GNN_DIM  256
#define HEADS    4
#define DH       64
#define N_PATCH  8192
#define N_TILES  128
#define N_EDGES  1024
#define N_TOT    (N_PATCH + N_TILES)   // 8320
#define NCHUNK   8                     // node chunks in phaseC
#define CHSZ     1040                  // nodes per chunk (8*1040 = 8320)
#define NTB      (N_TOT / 8)           // 1040 bytes per HTb row
#define NEB      (N_EDGES / 8)         // 128 bytes per HNb row
#define EWP      1028                  // padded per-head weight stride (phaseE)
#define CROW     260                   // ints per phaseC CSR row (<<9-shifted)
#define EROW     1040                  // ints per phaseE CSR row (node 0 has 1024 edges!)

typedef short  bf16x8 __attribute__((ext_vector_type(8)));
typedef float  f32x4  __attribute__((ext_vector_type(4)));

// ---------------------------------------------------------------------------
__device__ __forceinline__ float waveReduce(float v) {
    #pragma unroll
    for (int o = 32; o > 0; o >>= 1) v += __shfl_down(v, o, 64);
    return v; // valid in lane 0 of each 64-wide wave
}

// ---------------------------------------------------------------------------
// prep1 (grid-partitioned):
//   [0, 8320)    : transposeH tile -> HTb/HNb bit masks
//   [8320, 8416) : castW0 tile
//   [8416, 8480) : castW1 tile
//   [8480, 9000) : castX0, 16 rows each
// ---------------------------------------------------------------------------
__global__ __launch_bounds__(256) void prep1(
    const float* __restrict__ H,
    unsigned char* __restrict__ HTb, unsigned char* __restrict__ HNb,
    const float* __restrict__ W0, __hip_bfloat16* __restrict__ Wt0,
    const float* __restrict__ W1, __hip_bfloat16* __restrict__ Wt1,
    const float* __restrict__ x, const float* __restrict__ ro,
    __hip_bfloat16* __restrict__ Xb)
{
    __shared__ unsigned char tb[32][33];
    __shared__ float tf[32][33];
    int b = blockIdx.x, tid = threadIdx.x;
    int tx = tid & 31, ty = tid >> 5;          // ty in 0..7

    if (b < 8320) {
        int n0 = (b % 260) * 32;
        int e0 = (b / 260) * 32;
        #pragma unroll
        for (int r = 0; r < 4; ++r) {
            int row = ty + r * 8;
            tb[row][tx] = (H[(size_t)(n0 + row) * N_EDGES + e0 + tx] > 0.f) ? 1 : 0;
        }
        __syncthreads();
        if (tid < 128) {            // HTb: 32 edges x 4 node-bytes
            int er = tid >> 2, g = tid & 3;
            unsigned v = 0;
            #pragma unroll
            for (int i = 0; i < 8; ++i) v |= (unsigned)tb[g * 8 + i][er] << i;
            HTb[(size_t)(e0 + er) * NTB + (n0 >> 3) + g] = (unsigned char)v;
        } else {                    // HNb: 32 nodes x 4 edge-bytes
            int id = tid - 128;
            int nr = id >> 2, g = id & 3;
            unsigned v = 0;
            #pragma unroll
            for (int i = 0; i < 8; ++i) v |= (unsigned)tb[nr][g * 8 + i] << i;
            HNb[(size_t)(n0 + nr) * NEB + (e0 >> 3) + g] = (unsigned char)v;
        }
    } else if (b < 8480) {
        const float* W; __hip_bfloat16* Wt; int K, k0, n0;
        if (b < 8416) {
            int i = b - 8320; W = W0; Wt = Wt0; K = IN_DIM;
            k0 = (i % 12) * 32; n0 = (i / 12) * 32;
        } else {
            int i = b - 8416; W = W1; Wt = Wt1; K = GNN_DIM;
            k0 = (i % 8) * 32; n0 = (i / 8) * 32;
        }
        #pragma unroll
        for (int r = 0; r < 4; ++r)
            tf[ty + r * 8][tx] = W[(size_t)(k0 + ty + r * 8) * GNN_DIM + n0 + tx];
        __syncthreads();
        #pragma unroll
        for (int r = 0; r < 4; ++r)
            Wt[(size_t)(n0 + ty + r * 8) * K + k0 + tx] =
                __float2bfloat16(tf[tx][ty + r * 8]);
    } else {
        int nb = (b - 8480) * 16;
        for (int r = 0; r < 16; ++r) {
            int n = nb + r;
            for (int k = tid; k < IN_DIM; k += 256) {
                float v = (n < N_PATCH) ? x[(size_t)n * IN_DIM + k] : ro[k];
                Xb[(size_t)n * IN_DIM + k] = __float2bfloat16(v);
            }
        }
    }
}

// ---------------------------------------------------------------------------
// prep2: static membership CSR (indices pre-shifted <<9 = byte row offsets).
//   [0, 8192)        : phaseC CSR for (chunk, e) from HTb
//   [8192, 16512)    : phaseE CSR per node from HNb
//   16512            : outrow inverse map of ro_ids
// ---------------------------------------------------------------------------
__global__ __launch_bounds__(256) void prep2(
    const unsigned char* __restrict__ HTb, const unsigned char* __restrict__ HNb,
    const int* __restrict__ ro_ids,
    int* __restrict__ cidx, int* __restrict__ ccnt,
    int* __restrict__ eidxg, int* __restrict__ ecnt, int* __restrict__ outrow)
{
    int b = blockIdx.x, tid = threadIdx.x;
    if (b < 8192) {
        __shared__ int cnt;
        __shared__ int lst[CROW];
        int chunk = b >> 10, e = b & 1023;
        if (tid == 0) cnt = 0;
        __syncthreads();
        if (tid < CHSZ / 8) {
            unsigned bb = HTb[(size_t)e * NTB + chunk * (CHSZ / 8) + tid];
            int nb = chunk * CHSZ + tid * 8;
            while (bb) {
                int i = __ffs(bb) - 1; bb &= bb - 1;
                int p = atomicAdd(&cnt, 1);
                if (p < 256) lst[p] = (nb + i) << 9;
            }
        }
        __syncthreads();
        int c = min(cnt, 256);
        int cP = (c + 3) & ~3;
        for (int i = tid; i < cP; i += 256)
            cidx[(size_t)b * CROW + i] = (i < c) ? lst[i] : 0;
        if (tid == 0) ccnt[b] = c;
    } else if (b < 16512) {
        int n = b - 8192;
        __shared__ int cnt;
        __shared__ int lst[EROW];
        if (tid == 0) cnt = 0;
        __syncthreads();
        if (tid < NEB) {
            unsigned bb = HNb[(size_t)n * NEB + tid];
            int eb = tid * 8;
            while (bb) {
                int i = __ffs(bb) - 1; bb &= bb - 1;
                int p = atomicAdd(&cnt, 1);
                lst[p] = (eb + i) << 9;
            }
        }
        __syncthreads();
        int c = cnt;
        int cP = (c + 3) & ~3;
        for (int i = tid; i < cP && i < EROW; i += 256)
            eidxg[(size_t)n * EROW + i] = (i < c) ? lst[i] : 0;
        if (tid == 0) ecnt[n] = c;
    } else {
        if (tid < N_TILES) {
            int r = ro_ids[tid] - N_PATCH;
            if (r >= 0 && r < N_TILES) outrow[r] = tid;
        }
    }
}

// ---------------------------------------------------------------------------
// Phase A (MFMA): h = Xb @ Wt^T + nemb[node_type]; fused s_src/s_dst/expL.
// ---------------------------------------------------------------------------
__global__ __launch_bounds__(256) void phaseA_mfma(
    const __hip_bfloat16* __restrict__ Xb,  // [N_TOT, K] bf16
    const __hip_bfloat16* __restrict__ Wt,  // [256, K] bf16
    int K, int KP,                          // KP = K+8 (LDS row stride)
    const float* __restrict__ nemb,
    const int* __restrict__ node_type,
    const float* __restrict__ asrc, const float* __restrict__ adst,
    const float* __restrict__ ebias,
    float* __restrict__ hP, __hip_bfloat16* __restrict__ hPb,
    float* __restrict__ expL, float* __restrict__ sdst)
{
    __shared__ char smem[16 * 260 * 4];     // 16.6 KB, union of xs / cs
    unsigned short* xs = (unsigned short*)smem;  // [16][KP] bf16 bits
    float* cs = (float*)smem;                    // [16][260] f32

    int tid = threadIdx.x;
    int n0 = blockIdx.x * 16;

    {
        int lr = tid >> 4, lc = tid & 15;
        for (int c = lc * 8; c < K; c += 128)
            *(uint4*)&xs[lr * KP + c] = *(const uint4*)&Xb[(size_t)(n0 + lr) * K + c];
    }
    __syncthreads();

    int wave = tid >> 6, lane = tid & 63;
    int lr16 = lane & 15, quad = lane >> 4;

    f32x4 acc[4];
    #pragma unroll
    for (int ct = 0; ct < 4; ++ct)
        acc[ct] = (f32x4){0.f, 0.f, 0.f, 0.f};

    for (int kc = 0; kc < K; kc += 32) {
        bf16x8 a = *(const bf16x8*)&xs[lr16 * KP + kc + quad * 8];
        #pragma unroll
        for (int ct = 0; ct < 4; ++ct) {
            int col = wave * 64 + ct * 16 + lr16;
            bf16x8 b = *(const bf16x8*)&Wt[(size_t)col * K + kc + quad * 8];
            acc[ct] = __builtin_amdgcn_mfma_f32_16x16x32_bf16(a, b, acc[ct], 0, 0, 0);
        }
    }
    __syncthreads();   // xs dead; reuse as cs

    #pragma unroll
    for (int ct = 0; ct < 4; ++ct)
        #pragma unroll
        for (int g = 0; g < 4; ++g)
            cs[(quad * 4 + g) * 260 + wave * 64 + ct * 16 + lr16] = acc[ct][g];
    __syncthreads();

    int j = tid, h = j >> 6, l2 = j & 63;
    float as = asrc[h * DH + l2];
    float ad = adst[h * DH + l2];
    float eb0 = ebias[0 * HEADS + h], eb1 = ebias[1 * HEADS + h], eb2 = ebias[2 * HEADS + h];
    for (int r = 0; r < 16; ++r) {
        int n = n0 + r;
        float hv = cs[r * 260 + j] + nemb[node_type[n] * GNN_DIM + j];
        hP[(size_t)n * GNN_DIM + j] = hv;
        hPb[(size_t)n * GNN_DIM + j] = __float2bfloat16(hv);
        float ss = waveReduce(hv * as);
        float sd = waveReduce(hv * ad);
        if (l2 == 0) {
            sdst[n * HEADS + h] = sd;
            float l0 = ss + eb0; l0 = l0 > 0.f ? l0 : 0.2f * l0;
            float l1 = ss + eb1; l1 = l1 > 0.f ? l1 : 0.2f * l1;
            float lc2 = ss + eb2; lc2 = lc2 > 0.f ? lc2 : 0.2f * lc2;
            expL[n * 12 + 0 * HEADS + h] = __expf(l0);
            expL[n * 12 + 1 * HEADS + h] = __expf(l1);
            expL[n * 12 + 2 * HEADS + h] = __expf(lc2);
        }
    }
}

// ---------------------------------------------------------------------------
// Phase C accumulate: 128 threads, 2 cols/thread. CSR member lists (no
// compaction); gather indices read at block-uniform addresses (scalar loads).
// ---------------------------------------------------------------------------
__global__ __launch_bounds__(128) void phaseC_acc(
    const int* __restrict__ cidx, const int* __restrict__ ccnt,
    const int* __restrict__ edge_type,
    const float* __restrict__ expL,          // [N,3,4]
    const __hip_bfloat16* __restrict__ hPb,  // [N,256] bf16
    float* __restrict__ macc,                // [NCHUNK,1024,256]
    float* __restrict__ Zacc)                // [NCHUNK,1024,4]
{
    int bid = blockIdx.x;
    int e = bid & 1023;
    int j = threadIdx.x, h = j >> 5;         // cols 2j, 2j+1; head = j>>5
    int te = edge_type[e];
    __shared__ float wh[4][CROW];            // 4.2 KB, padded stride
    const int* csr = cidx + (size_t)bid * CROW;
    int c = ccnt[bid];
    int cP = (c + 3) & ~3;
    for (int i = j; i < c; i += 128) {
        int n = csr[i] >> 9;
        float4 w = *(const float4*)&expL[n * 12 + te * 4];
        wh[0][i] = w.x; wh[1][i] = w.y; wh[2][i] = w.z; wh[3][i] = w.w;
    }
    if (j < 4) {
        int i = c + j;
        if (i < cP) { wh[0][i] = wh[1][i] = wh[2][i] = wh[3][i] = 0.f; }
    }
    __syncthreads();
    {   // deterministic per-head Z (32-lane segments within each wave)
        float p = 0.f;
        for (int i = (j & 31); i < c; i += 32) p += wh[h][i];
        #pragma unroll
        for (int o = 16; o > 0; o >>= 1) p += __shfl_down(p, o, 32);
        if ((j & 31) == 0) Zacc[bid * HEADS + h] = p;
    }
    const char* hb = (const char*)hPb;
    int coff = j * 4;
    float al0 = 0.f, ah0 = 0.f, al1 = 0.f, ah1 = 0.f;
    for (int i = 0; i < cP; i += 4) {
        int4   n4 = *(const int4*)&csr[i];       // uniform -> s_load
        float4 w4 = *(const float4*)&wh[h][i];
        unsigned u0 = *(const unsigned*)(hb + n4.x + coff);
        unsigned u1 = *(const unsigned*)(hb + n4.y + coff);
        unsigned u2 = *(const unsigned*)(hb + n4.z + coff);
        unsigned u3 = *(const unsigned*)(hb + n4.w + coff);
        al0 += w4.x * __uint_as_float(u0 << 16);
        ah0 += w4.x * __uint_as_float(u0 & 0xffff0000u);
        al1 += w4.y * __uint_as_float(u1 << 16);
        ah1 += w4.y * __uint_as_float(u1 & 0xffff0000u);
        al0 += w4.z * __uint_as_float(u2 << 16);
        ah0 += w4.z * __uint_as_float(u2 & 0xffff0000u);
        al1 += w4.w * __uint_as_float(u3 << 16);
        ah1 += w4.w * __uint_as_float(u3 & 0xffff0000u);
    }
    float2 r; r.x = al0 + al1; r.y = ah0 + ah1;
    *(float2*)&macc[(size_t)bid * GNN_DIM + 2 * j] = r;
}

// ---------------------------------------------------------------------------
// Phase C reduce: combine NCHUNK partials, normalize, emit bf16 m + sedg.
// ---------------------------------------------------------------------------
__global__ __launch_bounds__(256) void phaseC_red(
    const float* __restrict__ macc,    // [NCHUNK,1024,256]
    const float* __restrict__ Zacc,    // [NCHUNK,1024,4]
    const float* __restrict__ aedg,    // [4,64]
    __hip_bfloat16* __restrict__ mb, float* __restrict__ sedg)
{
    int e = blockIdx.x, j = threadIdx.x, h = j >> 6, lane = j & 63;
    float s = 0.f, Z = 0.f;
    #pragma unroll
    for (int c = 0; c < NCHUNK; ++c) {
        s += macc[(size_t)((c << 10) + e) * GNN_DIM + j];
        Z += Zacc[((c << 10) + e) * HEADS + h];
    }
    float mv = s / Z;
    mb[(size_t)e * GNN_DIM + j] = __float2bfloat16(mv);
    float se = waveReduce(mv * aedg[h * DH + lane]);
    if (lane == 0) sedg[e * HEADS + h] = se;
}

// ---------------------------------------------------------------------------
// Phase E (layer 0): one block per node, 256 threads, 1 col/thread.
// CSR edge lists (no compaction); gather indices via uniform scalar loads;
// weights staged head-major padded. hOut skipped if null (dead in layer 0).
// ---------------------------------------------------------------------------
__global__ __launch_bounds__(256) void phaseE(
    const int* __restrict__ eidxg, const int* __restrict__ ecnt,
    const float* __restrict__ sdstArr,       // [N,4]
    const float* __restrict__ sedg,          // [E,4]
    const __hip_bfloat16* __restrict__ mb,   // [E,256] bf16
    const float* __restrict__ hP,            // [N,256] residual
    float* __restrict__ hOut, __hip_bfloat16* __restrict__ hOutb)
{
    int n = blockIdx.x, j = threadIdx.x, h = j >> 6;
    __shared__ float wh[4][EWP];             // 16.4 KB, padded head-major
    __shared__ float sdv[4];
    if (j < 4) sdv[j] = sdstArr[n * HEADS + j];
    __syncthreads();
    const int* ecsr = eidxg + (size_t)n * EROW;
    int c = ecnt[n];
    int cP = (c + 3) & ~3;
    for (int i = j; i < c; i += 256) {
        int e = ecsr[i] >> 9;
        float4 sg = *(const float4*)&sedg[e * 4];
        float l0 = sdv[0] + sg.x; l0 = l0 > 0.f ? l0 : 0.2f * l0;
        float l1 = sdv[1] + sg.y; l1 = l1 > 0.f ? l1 : 0.2f * l1;
        float l2 = sdv[2] + sg.z; l2 = l2 > 0.f ? l2 : 0.2f * l2;
        float l3 = sdv[3] + sg.w; l3 = l3 > 0.f ? l3 : 0.2f * l3;
        wh[0][i] = __expf(l0); wh[1][i] = __expf(l1);
        wh[2][i] = __expf(l2); wh[3][i] = __expf(l3);
    }
    if (j < 4) {
        int i = c + j;
        if (i < cP) { wh[0][i] = wh[1][i] = wh[2][i] = wh[3][i] = 0.f; }
    }
    __syncthreads();

    float zp = 0.f;
    for (int i = (j & 63); i < c; i += 64) zp += wh[h][i];
    zp = waveReduce(zp);
    float Z = __shfl(zp, 0, 64);

    float a0 = 0.f, a1 = 0.f, a2 = 0.f, a3 = 0.f;
    const char* mbB = (const char*)mb;
    int coff = j * 4 & ~3;  // byte offset of col pair base; use 2B col offset below
    (void)coff;
    int i = 0;
    for (; i + 3 < c || (i < cP && i + 3 < cP); i += 4) {
        int4 e4 = *(const int4*)&ecsr[i];        // uniform -> s_load
        float4 w4 = *(const float4*)&wh[h][i];
        a0 += w4.x * (float)*(const __hip_bfloat16*)(mbB + e4.x + j * 2);
        a1 += w4.y * (float)*(const __hip_bfloat16*)(mbB + e4.y + j * 2);
        a2 += w4.z * (float)*(const __hip_bfloat16*)(mbB + e4.z + j * 2);
        a3 += w4.w * (float)*(const __hip_bfloat16*)(mbB + e4.w + j * 2);
    }
    float o = ((a0 + a1) + (a2 + a3)) / Z;
    o = o > 0.f ? o : expm1f(o);   // ELU (alpha=1)
    float res = o + hP[(size_t)n * GNN_DIM + j];
    if (hOut) hOut[(size_t)n * GNN_DIM + j] = res;
    hOutb[(size_t)n * GNN_DIM + j] = __float2bfloat16(res);
}

// ---------------------------------------------------------------------------
// Phase E last (layer 1): same gather + fused final layernorm -> d_out.
// ---------------------------------------------------------------------------
__global__ __launch_bounds__(256) void phaseE_last(
    const int* __restrict__ eidxg, const int* __restrict__ ecnt,
    const float* __restrict__ sdstArr,
    const float* __restrict__ sedg,
    const __hip_bfloat16* __restrict__ mb,
    const float* __restrict__ hP,
    const float* __restrict__ ng, const float* __restrict__ nb,
    const float* __restrict__ bg, const float* __restrict__ bb,
    const int* __restrict__ outrow,
    float* __restrict__ out)
{
    int n = blockIdx.x, j = threadIdx.x, h = j >> 6, lane = j & 63;
    __shared__ float wh[4][EWP];
    __shared__ float sdv[4];
    __shared__ float red[4];
    if (j < 4) sdv[j] = sdstArr[n * HEADS + j];
    __syncthreads();
    const int* ecsr = eidxg + (size_t)n * EROW;
    int c = ecnt[n];
    int cP = (c + 3) & ~3;
    for (int i = j; i < c; i += 256) {
        int e = ecsr[i] >> 9;
        float4 sg = *(const float4*)&sedg[e * 4];
        float l0 = sdv[0] + sg.x; l0 = l0 > 0.f ? l0 : 0.2f * l0;
        float l1 = sdv[1] + sg.y; l1 = l1 > 0.f ? l1 : 0.2f * l1;
        float l2 = sdv[2] + sg.z; l2 = l2 > 0.f ? l2 : 0.2f * l2;
        float l3 = sdv[3] + sg.w; l3 = l3 > 0.f ? l3 : 0.2f * l3;
        wh[0][i] = __expf(l0); wh[1][i] = __expf(l1);
        wh[2][i] = __expf(l2); wh[3][i] = __expf(l3);
    }
    if (j < 4) {
        int i = c + j;
        if (i < cP) { wh[0][i] = wh[1][i] = wh[2][i] = wh[3][i] = 0.f; }
    }
    __syncthreads();

    float zp = 0.f;
    for (int i = (j & 63); i < c; i += 64) zp += wh[h][i];
    zp = waveReduce(zp);
    float Z = __shfl(zp, 0, 64);

    float a0 = 0.f, a1 = 0.f, a2 = 0.f, a3 = 0.f;
    const char* mbB = (const char*)mb;
    int i = 0;
    for (; i + 3 < cP; i += 4) {
        int4 e4 = *(const int4*)&ecsr[i];
        float4 w4 = *(const float4*)&wh[h][i];
        a0 += w4.x * (float)*(const __hip_bfloat16*)(mbB + e4.x + j * 2);
        a1 += w4.y * (float)*(const __hip_bfloat16*)(mbB + e4.y + j * 2);
        a2 += w4.z * (float)*(const __hip_bfloat16*)(mbB + e4.z + j * 2);
        a3 += w4.w * (float)*(const __hip_bfloat16*)(mbB + e4.w + j * 2);
    }
    float o = ((a0 + a1) + (a2 + a3)) / Z;
    o = o > 0.f ? o : expm1f(o);
    float res = o + hP[(size_t)n * GNN_DIM + j];

    // fused layernorm over the 256 columns of this node
    float s1 = waveReduce(res);
    if (lane == 0) red[h] = s1;
    __syncthreads();
    float mean = (red[0] + red[1] + red[2] + red[3]) * (1.f / GNN_DIM);
    __syncthreads();
    float d = res - mean;
    float s2 = waveReduce(d * d);
    if (lane == 0) red[h] = s2;
    __syncthreads();
    float var = (red[0] + red[1] + red[2] + red[3]) * (1.f / GNN_DIM);
    const float* g; const float* bta; size_t outOff;
    if (n < N_PATCH) { g = ng; bta = nb; outOff = (size_t)n * GNN_DIM; }
    else {
        int q = outrow[n - N_PATCH];
        g = bg; bta = bb;
        outOff = (size_t)(N_PATCH + q) * GNN_DIM;
    }
    out[outOff + j] = d * rsqrtf(var + 1e-5f) * g[j] + bta[j];
}

// ---------------------------------------------------------------------------
extern "C" void kernel_launch(void* const* d_in, const int* in_sizes, int n_in,
                              void* d_out, int out_size, void* d_ws, size_t ws_size,
                              hipStream_t stream) {
    const float* x_nodes   = (const float*)d_in[0];
    const float* readout   = (const float*)d_in[1];
    const int*   node_type = (const int*)d_in[2];
    const int*   edge_type = (const int*)d_in[3];
    const float* Hmat      = (const float*)d_in[4];
    const int*   ro_ids    = (const int*)d_in[5];
    const float* W0        = (const float*)d_in[6];
    const float* W1        = (const float*)d_in[7];
    const float* node_emb  = (const float*)d_in[8];
    const float* a_src     = (const float*)d_in[9];
    const float* a_dst     = (const float*)d_in[10];
    const float* a_edge    = (const float*)d_in[11];
    const float* edge_bias = (const float*)d_in[12];
    const float* node_g    = (const float*)d_in[13];
    const float* node_b    = (const float*)d_in[14];
    const float* bag_g     = (const float*)d_in[15];
    const float* bag_b     = (const float*)d_in[16];

    // Workspace layout (~75 MB). Aliases: macc = hX (hX otherwise unused now);
    // hXb = Xb0 (Xb0 dead after layer-0 phaseA).
    char* ws = (char*)d_ws;
    size_t off = 0;
    unsigned char* HTb = (unsigned char*)(ws + off); off += (size_t)N_EDGES * NTB;
    unsigned char* HNb = (unsigned char*)(ws + off); off += (size_t)N_TOT * NEB;
    off = (off + 255) & ~(size_t)255;
    float* hP   = (float*)(ws + off); off += (size_t)N_TOT * GNN_DIM * 4;
    float* hX   = (float*)(ws + off); off += (size_t)N_TOT * GNN_DIM * 4;
    __hip_bfloat16* hPb = (__hip_bfloat16*)(ws + off); off += (size_t)N_TOT * GNN_DIM * 2;
    __hip_bfloat16* mb  = (__hip_bfloat16*)(ws + off); off += (size_t)N_EDGES * GNN_DIM * 2;
    __hip_bfloat16* Xb0 = (__hip_bfloat16*)(ws + off); off += (size_t)N_TOT * IN_DIM * 2;
    __hip_bfloat16* Wt0 = (__hip_bfloat16*)(ws + off); off += (size_t)GNN_DIM * IN_DIM * 2;
    __hip_bfloat16* Wt1 = (__hip_bfloat16*)(ws + off); off += (size_t)GNN_DIM * GNN_DIM * 2;
    float* expL = (float*)(ws + off); off += (size_t)N_TOT * 12 * 4;
    float* sdst = (float*)(ws + off); off += (size_t)N_TOT * HEADS * 4;
    float* sedg = (float*)(ws + off); off += (size_t)N_EDGES * HEADS * 4;
    float* Zacc = (float*)(ws + off); off += (size_t)NCHUNK * 1024 * HEADS * 4;
    off = (off + 255) & ~(size_t)255;
    int* cidx  = (int*)(ws + off); off += (size_t)NCHUNK * 1024 * CROW * 4;   // 8.5 MB
    int* ccnt  = (int*)(ws + off); off += (size_t)NCHUNK * 1024 * 4;
    int* eidxg = (int*)(ws + off); off += (size_t)N_TOT * EROW * 4;           // 34.6 MB
    int* ecnt  = (int*)(ws + off); off += (size_t)N_TOT * 4;
    int* outrow = (int*)(ws + off); off += N_TILES * 4;
    float* macc = hX;                        // alias
    __hip_bfloat16* hXb = Xb0;               // alias

    // ----- prep -----
    prep1<<<9000, 256, 0, stream>>>(Hmat, HTb, HNb, W0, Wt0, W1, Wt1,
                                    x_nodes, readout, Xb0);
    prep2<<<16513, 256, 0, stream>>>(HTb, HNb, ro_ids,
                                     cidx, ccnt, eidxg, ecnt, outrow);

    // ----- layer 0 -----
    phaseA_mfma<<<N_TOT / 16, 256, 0, stream>>>(Xb0, Wt0, IN_DIM, IN_DIM + 8,
                                      node_emb, node_type,
                                      a_src, a_dst, edge_bias,
                                      hP, hPb, expL, sdst);
    phaseC_acc<<<NCHUNK * 1024, 128, 0, stream>>>(cidx, ccnt, edge_type, expL,
                                                  hPb, macc, Zacc);
    phaseC_red<<<N_EDGES, 256, 0, stream>>>(macc, Zacc, a_edge, mb, sedg);
    phaseE<<<N_TOT, 256, 0, stream>>>(eidxg, ecnt, sdst, sedg, mb, hP,
                                      nullptr, hXb);

    // ----- layer 1 -----
    phaseA_mfma<<<N_TOT / 16, 256, 0, stream>>>(hXb, Wt1, GNN_DIM, GNN_DIM + 8,
                                      node_emb + 4 * GNN_DIM, node_type,
                                      a_src + HEADS * DH, a_dst + HEADS * DH,
                                      edge_bias + 12,
                                      hP, hPb, expL, sdst);
    phaseC_acc<<<NCHUNK * 1024, 128, 0, stream>>>(cidx, ccnt, edge_type, expL,
                                                  hPb, macc, Zacc);
    phaseC_red<<<N_EDGES, 256, 0, stream>>>(macc, Zacc, a_edge + HEADS * DH, mb, sedg);
    phaseE_last<<<N_TOT, 256, 0, stream>>>(eidxg, ecnt, sdst, sedg, mb, hP,
                                           node_g, node_b, bag_g, bag_b, outrow,
                                           (float*)d_out);
}

// Round 17
// 298.626 us; speedup vs baseline: 1.1201x; 1.1201x over previous
//
#include <hip/hip_runtime.h>
#include <hip/hip_bf16.h>
#include <math.h>

// Problem constants
#define IN_DIM   384
#define GNN_DIM  256
#define HEADS    4
#define DH       64
#define N_PATCH  8192
#define N_TILES  128
#define N_EDGES  1024
#define N_TOT    (N_PATCH + N_TILES)   // 8320
#define NCHUNK   8                     // node chunks in phaseC
#define CHSZ     1040                  // nodes per chunk (8*1040 = 8320)
#define NTB      (N_TOT / 8)           // 1040 bytes per HTb row
#define NEB      (N_EDGES / 8)         // 128 bytes per HNb row
#define EWP      1028                  // padded per-head weight stride (phaseE)

typedef short  bf16x8 __attribute__((ext_vector_type(8)));
typedef float  f32x4  __attribute__((ext_vector_type(4)));

// ---------------------------------------------------------------------------
__device__ __forceinline__ float waveReduce(float v) {
    #pragma unroll
    for (int o = 32; o > 0; o >>= 1) v += __shfl_down(v, o, 64);
    return v; // valid in lane 0 of each 64-wide wave
}

// ---------------------------------------------------------------------------
// Fused prep kernel (grid-partitioned):
//   blocks [0, 8320)    : transposeH tile -> HTb/HNb bit masks
//   blocks [8320, 8416) : castW0 tile
//   blocks [8416, 8480) : castW1 tile
//   blocks [8480, 9000) : castX0, 16 rows each
//   block  9000         : outrow inverse map of ro_ids
// ---------------------------------------------------------------------------
__global__ __launch_bounds__(256) void prep1(
    const float* __restrict__ H,
    unsigned char* __restrict__ HTb, unsigned char* __restrict__ HNb,
    const float* __restrict__ W0, __hip_bfloat16* __restrict__ Wt0,
    const float* __restrict__ W1, __hip_bfloat16* __restrict__ Wt1,
    const float* __restrict__ x, const float* __restrict__ ro,
    __hip_bfloat16* __restrict__ Xb,
    const int* __restrict__ ro_ids, int* __restrict__ outrow)
{
    __shared__ unsigned char tb[32][33];
    __shared__ float tf[32][33];
    int b = blockIdx.x, tid = threadIdx.x;
    int tx = tid & 31, ty = tid >> 5;          // ty in 0..7

    if (b < 8320) {
        int n0 = (b % 260) * 32;
        int e0 = (b / 260) * 32;
        #pragma unroll
        for (int r = 0; r < 4; ++r) {
            int row = ty + r * 8;
            tb[row][tx] = (H[(size_t)(n0 + row) * N_EDGES + e0 + tx] > 0.f) ? 1 : 0;
        }
        __syncthreads();
        if (tid < 128) {            // HTb: 32 edges x 4 node-bytes
            int er = tid >> 2, g = tid & 3;
            unsigned v = 0;
            #pragma unroll
            for (int i = 0; i < 8; ++i) v |= (unsigned)tb[g * 8 + i][er] << i;
            HTb[(size_t)(e0 + er) * NTB + (n0 >> 3) + g] = (unsigned char)v;
        } else {                    // HNb: 32 nodes x 4 edge-bytes
            int id = tid - 128;
            int nr = id >> 2, g = id & 3;
            unsigned v = 0;
            #pragma unroll
            for (int i = 0; i < 8; ++i) v |= (unsigned)tb[nr][g * 8 + i] << i;
            HNb[(size_t)(n0 + nr) * NEB + (e0 >> 3) + g] = (unsigned char)v;
        }
    } else if (b < 8480) {
        const float* W; __hip_bfloat16* Wt; int K, k0, n0;
        if (b < 8416) {
            int i = b - 8320; W = W0; Wt = Wt0; K = IN_DIM;
            k0 = (i % 12) * 32; n0 = (i / 12) * 32;
        } else {
            int i = b - 8416; W = W1; Wt = Wt1; K = GNN_DIM;
            k0 = (i % 8) * 32; n0 = (i / 8) * 32;
        }
        #pragma unroll
        for (int r = 0; r < 4; ++r)
            tf[ty + r * 8][tx] = W[(size_t)(k0 + ty + r * 8) * GNN_DIM + n0 + tx];
        __syncthreads();
        #pragma unroll
        for (int r = 0; r < 4; ++r)
            Wt[(size_t)(n0 + ty + r * 8) * K + k0 + tx] =
                __float2bfloat16(tf[tx][ty + r * 8]);
    } else if (b < 9000) {
        int nb = (b - 8480) * 16;
        for (int r = 0; r < 16; ++r) {
            int n = nb + r;
            for (int k = tid; k < IN_DIM; k += 256) {
                float v = (n < N_PATCH) ? x[(size_t)n * IN_DIM + k] : ro[k];
                Xb[(size_t)n * IN_DIM + k] = __float2bfloat16(v);
            }
        }
    } else {
        if (tid < N_TILES) {
            int r = ro_ids[tid] - N_PATCH;
            if (r >= 0 && r < N_TILES) outrow[r] = tid;
        }
    }
}

// ---------------------------------------------------------------------------
// Phase A (MFMA): h = Xb @ Wt^T + nemb[node_type]; fused s_src/s_dst/expL.
// ---------------------------------------------------------------------------
__global__ __launch_bounds__(256) void phaseA_mfma(
    const __hip_bfloat16* __restrict__ Xb,  // [N_TOT, K] bf16
    const __hip_bfloat16* __restrict__ Wt,  // [256, K] bf16
    int K, int KP,                          // KP = K+8 (LDS row stride)
    const float* __restrict__ nemb,
    const int* __restrict__ node_type,
    const float* __restrict__ asrc, const float* __restrict__ adst,
    const float* __restrict__ ebias,
    float* __restrict__ hP, __hip_bfloat16* __restrict__ hPb,
    float* __restrict__ expL, float* __restrict__ sdst)
{
    __shared__ char smem[16 * 260 * 4];     // 16.6 KB, union of xs / cs
    unsigned short* xs = (unsigned short*)smem;  // [16][KP] bf16 bits
    float* cs = (float*)smem;                    // [16][260] f32

    int tid = threadIdx.x;
    int n0 = blockIdx.x * 16;

    {
        int lr = tid >> 4, lc = tid & 15;
        for (int c = lc * 8; c < K; c += 128)
            *(uint4*)&xs[lr * KP + c] = *(const uint4*)&Xb[(size_t)(n0 + lr) * K + c];
    }
    __syncthreads();

    int wave = tid >> 6, lane = tid & 63;
    int lr16 = lane & 15, quad = lane >> 4;

    f32x4 acc[4];
    #pragma unroll
    for (int ct = 0; ct < 4; ++ct)
        acc[ct] = (f32x4){0.f, 0.f, 0.f, 0.f};

    for (int kc = 0; kc < K; kc += 32) {
        bf16x8 a = *(const bf16x8*)&xs[lr16 * KP + kc + quad * 8];
        #pragma unroll
        for (int ct = 0; ct < 4; ++ct) {
            int col = wave * 64 + ct * 16 + lr16;
            bf16x8 b = *(const bf16x8*)&Wt[(size_t)col * K + kc + quad * 8];
            acc[ct] = __builtin_amdgcn_mfma_f32_16x16x32_bf16(a, b, acc[ct], 0, 0, 0);
        }
    }
    __syncthreads();   // xs dead; reuse as cs

    #pragma unroll
    for (int ct = 0; ct < 4; ++ct)
        #pragma unroll
        for (int g = 0; g < 4; ++g)
            cs[(quad * 4 + g) * 260 + wave * 64 + ct * 16 + lr16] = acc[ct][g];
    __syncthreads();

    int j = tid, h = j >> 6, l2 = j & 63;
    float as = asrc[h * DH + l2];
    float ad = adst[h * DH + l2];
    float eb0 = ebias[0 * HEADS + h], eb1 = ebias[1 * HEADS + h], eb2 = ebias[2 * HEADS + h];
    for (int r = 0; r < 16; ++r) {
        int n = n0 + r;
        float hv = cs[r * 260 + j] + nemb[node_type[n] * GNN_DIM + j];
        hP[(size_t)n * GNN_DIM + j] = hv;
        hPb[(size_t)n * GNN_DIM + j] = __float2bfloat16(hv);
        float ss = waveReduce(hv * as);
        float sd = waveReduce(hv * ad);
        if (l2 == 0) {
            sdst[n * HEADS + h] = sd;
            float l0 = ss + eb0; l0 = l0 > 0.f ? l0 : 0.2f * l0;
            float l1 = ss + eb1; l1 = l1 > 0.f ? l1 : 0.2f * l1;
            float lc2 = ss + eb2; lc2 = lc2 > 0.f ? lc2 : 0.2f * lc2;
            expL[n * 12 + 0 * HEADS + h] = __expf(l0);
            expL[n * 12 + 1 * HEADS + h] = __expf(l1);
            expL[n * 12 + 2 * HEADS + h] = __expf(lc2);
        }
    }
}

// ---------------------------------------------------------------------------
// Phase C accumulate: 128 threads, 2 cols/thread (packed uint bf16 loads).
// LDS bit-scan compaction (measured best); wh padded stride 260.
// ---------------------------------------------------------------------------
__global__ __launch_bounds__(128) void phaseC_acc(
    const unsigned char* __restrict__ HTb,   // [E, N_TOT/8] bits
    const int* __restrict__ edge_type,
    const float* __restrict__ expL,          // [N,3,4]
    const __hip_bfloat16* __restrict__ hPb,  // [N,256] bf16
    float* __restrict__ macc,                // [NCHUNK,1024,256]
    float* __restrict__ Zacc)                // [NCHUNK,1024,4]
{
    int bid = blockIdx.x;
    int chunk = bid >> 10, e = bid & 1023;
    int j = threadIdx.x, h = j >> 5;         // cols 2j, 2j+1; head = j>>5
    int te = edge_type[e];
    __shared__ int cnt;
    __shared__ int   noff[256];
    __shared__ float wh[4][260];             // padded stride (bank-conflict fix)
    if (j == 0) cnt = 0;
    __syncthreads();
    for (int jj = j; jj < CHSZ / 8; jj += 128) {
        unsigned b = HTb[(size_t)e * NTB + chunk * (CHSZ / 8) + jj];
        int nb = chunk * CHSZ + jj * 8;
        while (b) {
            int i = __ffs(b) - 1; b &= b - 1;
            int p = atomicAdd(&cnt, 1);
            if (p < 256) noff[p] = (nb + i) << 9;
        }
    }
    __syncthreads();
    int c = min(cnt, 256);
    int cP = (c + 3) & ~3;
    for (int i = j; i < c; i += 128) {
        int n = noff[i] >> 9;
        float4 w = *(const float4*)&expL[n * 12 + te * 4];
        wh[0][i] = w.x; wh[1][i] = w.y; wh[2][i] = w.z; wh[3][i] = w.w;
    }
    if (j < 4) {
        int i = c + j;
        if (i < cP) { noff[i] = 0; wh[0][i] = wh[1][i] = wh[2][i] = wh[3][i] = 0.f; }
    }
    __syncthreads();
    {   // deterministic per-head Z (32-lane segments within each wave)
        float p = 0.f;
        for (int i = (j & 31); i < c; i += 32) p += wh[h][i];
        #pragma unroll
        for (int o = 16; o > 0; o >>= 1) p += __shfl_down(p, o, 32);
        if ((j & 31) == 0) Zacc[bid * HEADS + h] = p;
    }
    const char* hb = (const char*)hPb;
    int coff = j * 4;
    float al0 = 0.f, ah0 = 0.f, al1 = 0.f, ah1 = 0.f;
    for (int i = 0; i < cP; i += 4) {
        int4   n4 = *(const int4*)&noff[i];
        float4 w4 = *(const float4*)&wh[h][i];
        unsigned u0 = *(const unsigned*)(hb + n4.x + coff);
        unsigned u1 = *(const unsigned*)(hb + n4.y + coff);
        unsigned u2 = *(const unsigned*)(hb + n4.z + coff);
        unsigned u3 = *(const unsigned*)(hb + n4.w + coff);
        al0 += w4.x * __uint_as_float(u0 << 16);
        ah0 += w4.x * __uint_as_float(u0 & 0xffff0000u);
        al1 += w4.y * __uint_as_float(u1 << 16);
        ah1 += w4.y * __uint_as_float(u1 & 0xffff0000u);
        al0 += w4.z * __uint_as_float(u2 << 16);
        ah0 += w4.z * __uint_as_float(u2 & 0xffff0000u);
        al1 += w4.w * __uint_as_float(u3 << 16);
        ah1 += w4.w * __uint_as_float(u3 & 0xffff0000u);
    }
    float2 r; r.x = al0 + al1; r.y = ah0 + ah1;
    *(float2*)&macc[(size_t)bid * GNN_DIM + 2 * j] = r;
}

// ---------------------------------------------------------------------------
// Phase C reduce: combine NCHUNK partials, normalize, emit bf16 m + sedg.
// ---------------------------------------------------------------------------
__global__ __launch_bounds__(256) void phaseC_red(
    const float* __restrict__ macc,    // [NCHUNK,1024,256]
    const float* __restrict__ Zacc,    // [NCHUNK,1024,4]
    const float* __restrict__ aedg,    // [4,64]
    __hip_bfloat16* __restrict__ mb, float* __restrict__ sedg)
{
    int e = blockIdx.x, j = threadIdx.x, h = j >> 6, lane = j & 63;
    float s = 0.f, Z = 0.f;
    #pragma unroll
    for (int c = 0; c < NCHUNK; ++c) {
        s += macc[(size_t)((c << 10) + e) * GNN_DIM + j];
        Z += Zacc[((c << 10) + e) * HEADS + h];
    }
    float mv = s / Z;
    mb[(size_t)e * GNN_DIM + j] = __float2bfloat16(mv);
    float se = waveReduce(mv * aedg[h * DH + lane]);
    if (lane == 0) sedg[e * HEADS + h] = se;
}

// ---------------------------------------------------------------------------
// Phase E (layer 0): R15 geometry — LDS bit-scan compaction, LDS eidx,
// padded head-major weights, per-wave Z. Writes bf16 hOutb only (f32 dead).
// ---------------------------------------------------------------------------
__global__ __launch_bounds__(256) void phaseE(
    const unsigned char* __restrict__ HNb,   // [N, E/8] bits
    const float* __restrict__ sdstArr,       // [N,4]
    const float* __restrict__ sedg,          // [E,4]
    const __hip_bfloat16* __restrict__ mb,   // [E,256] bf16
    const float* __restrict__ hP,            // [N,256] residual
    __hip_bfloat16* __restrict__ hOutb)
{
    int n = blockIdx.x, j = threadIdx.x, h = j >> 6;
    __shared__ int cnt;
    __shared__ int   eidx[N_EDGES];          // 4 KB
    __shared__ float wh[4][EWP];             // 16.4 KB, padded head-major
    __shared__ float sdv[4];
    if (j < 4) sdv[j] = sdstArr[n * HEADS + j];
    if (j == 0) cnt = 0;
    __syncthreads();
    if (j < NEB) {
        unsigned b = HNb[(size_t)n * NEB + j];
        while (b) {
            int i = __ffs(b) - 1; b &= b - 1;
            int p = atomicAdd(&cnt, 1);
            eidx[p] = j * 8 + i;
        }
    }
    __syncthreads();
    int c = cnt;
    for (int i = j; i < c; i += 256) {
        int e = eidx[i];
        float4 sg = *(const float4*)&sedg[e * 4];
        float l0 = sdv[0] + sg.x; l0 = l0 > 0.f ? l0 : 0.2f * l0;
        float l1 = sdv[1] + sg.y; l1 = l1 > 0.f ? l1 : 0.2f * l1;
        float l2 = sdv[2] + sg.z; l2 = l2 > 0.f ? l2 : 0.2f * l2;
        float l3 = sdv[3] + sg.w; l3 = l3 > 0.f ? l3 : 0.2f * l3;
        wh[0][i] = __expf(l0); wh[1][i] = __expf(l1);
        wh[2][i] = __expf(l2); wh[3][i] = __expf(l3);
    }
    __syncthreads();

    float zp = 0.f;
    for (int i = (j & 63); i < c; i += 64) zp += wh[h][i];
    zp = waveReduce(zp);
    float Z = __shfl(zp, 0, 64);

    float a0 = 0.f, a1 = 0.f, a2 = 0.f, a3 = 0.f;
    int i = 0;
    for (; i + 3 < c; i += 4) {
        int e_0 = eidx[i], e_1 = eidx[i+1], e_2 = eidx[i+2], e_3 = eidx[i+3];
        float4 w4 = *(const float4*)&wh[h][i];   // b128 broadcast
        a0 += w4.x * (float)mb[(size_t)e_0 * GNN_DIM + j];
        a1 += w4.y * (float)mb[(size_t)e_1 * GNN_DIM + j];
        a2 += w4.z * (float)mb[(size_t)e_2 * GNN_DIM + j];
        a3 += w4.w * (float)mb[(size_t)e_3 * GNN_DIM + j];
    }
    for (; i < c; ++i) {
        int ee = eidx[i];
        a0 += wh[h][i] * (float)mb[(size_t)ee * GNN_DIM + j];
    }
    float o = ((a0 + a1) + (a2 + a3)) / Z;
    o = o > 0.f ? o : expm1f(o);   // ELU (alpha=1)
    float res = o + hP[(size_t)n * GNN_DIM + j];
    hOutb[(size_t)n * GNN_DIM + j] = __float2bfloat16(res);
}

// ---------------------------------------------------------------------------
// Phase E last (layer 1): same gather body + fused final layernorm -> d_out.
// ---------------------------------------------------------------------------
__global__ __launch_bounds__(256) void phaseE_last(
    const unsigned char* __restrict__ HNb,
    const float* __restrict__ sdstArr,
    const float* __restrict__ sedg,
    const __hip_bfloat16* __restrict__ mb,
    const float* __restrict__ hP,
    const float* __restrict__ ng, const float* __restrict__ nb,
    const float* __restrict__ bg, const float* __restrict__ bb,
    const int* __restrict__ outrow,
    float* __restrict__ out)
{
    int n = blockIdx.x, j = threadIdx.x, h = j >> 6, lane = j & 63;
    __shared__ int cnt;
    __shared__ int   eidx[N_EDGES];
    __shared__ float wh[4][EWP];
    __shared__ float sdv[4];
    __shared__ float red[4];
    if (j < 4) sdv[j] = sdstArr[n * HEADS + j];
    if (j == 0) cnt = 0;
    __syncthreads();
    if (j < NEB) {
        unsigned b = HNb[(size_t)n * NEB + j];
        while (b) {
            int i = __ffs(b) - 1; b &= b - 1;
            int p = atomicAdd(&cnt, 1);
            eidx[p] = j * 8 + i;
        }
    }
    __syncthreads();
    int c = cnt;
    for (int i = j; i < c; i += 256) {
        int e = eidx[i];
        float4 sg = *(const float4*)&sedg[e * 4];
        float l0 = sdv[0] + sg.x; l0 = l0 > 0.f ? l0 : 0.2f * l0;
        float l1 = sdv[1] + sg.y; l1 = l1 > 0.f ? l1 : 0.2f * l1;
        float l2 = sdv[2] + sg.z; l2 = l2 > 0.f ? l2 : 0.2f * l2;
        float l3 = sdv[3] + sg.w; l3 = l3 > 0.f ? l3 : 0.2f * l3;
        wh[0][i] = __expf(l0); wh[1][i] = __expf(l1);
        wh[2][i] = __expf(l2); wh[3][i] = __expf(l3);
    }
    __syncthreads();

    float zp = 0.f;
    for (int i = (j & 63); i < c; i += 64) zp += wh[h][i];
    zp = waveReduce(zp);
    float Z = __shfl(zp, 0, 64);

    float a0 = 0.f, a1 = 0.f, a2 = 0.f, a3 = 0.f;
    int i = 0;
    for (; i + 3 < c; i += 4) {
        int e_0 = eidx[i], e_1 = eidx[i+1], e_2 = eidx[i+2], e_3 = eidx[i+3];
        float4 w4 = *(const float4*)&wh[h][i];
        a0 += w4.x * (float)mb[(size_t)e_0 * GNN_DIM + j];
        a1 += w4.y * (float)mb[(size_t)e_1 * GNN_DIM + j];
        a2 += w4.z * (float)mb[(size_t)e_2 * GNN_DIM + j];
        a3 += w4.w * (float)mb[(size_t)e_3 * GNN_DIM + j];
    }
    for (; i < c; ++i) {
        int ee = eidx[i];
        a0 += wh[h][i] * (float)mb[(size_t)ee * GNN_DIM + j];
    }
    float o = ((a0 + a1) + (a2 + a3)) / Z;
    o = o > 0.f ? o : expm1f(o);
    float res = o + hP[(size_t)n * GNN_DIM + j];

    // fused layernorm over this node's 256 columns
    float s1 = waveReduce(res);
    if (lane == 0) red[h] = s1;
    __syncthreads();
    float mean = (red[0] + red[1] + red[2] + red[3]) * (1.f / GNN_DIM);
    __syncthreads();
    float d = res - mean;
    float s2 = waveReduce(d * d);
    if (lane == 0) red[h] = s2;
    __syncthreads();
    float var = (red[0] + red[1] + red[2] + red[3]) * (1.f / GNN_DIM);
    const float* g; const float* bta; size_t outOff;
    if (n < N_PATCH) { g = ng; bta = nb; outOff = (size_t)n * GNN_DIM; }
    else {
        int q = outrow[n - N_PATCH];
        g = bg; bta = bb;
        outOff = (size_t)(N_PATCH + q) * GNN_DIM;
    }
    out[outOff + j] = d * rsqrtf(var + 1e-5f) * g[j] + bta[j];
}

// ---------------------------------------------------------------------------
extern "C" void kernel_launch(void* const* d_in, const int* in_sizes, int n_in,
                              void* d_out, int out_size, void* d_ws, size_t ws_size,
                              hipStream_t stream) {
    const float* x_nodes   = (const float*)d_in[0];
    const float* readout   = (const float*)d_in[1];
    const int*   node_type = (const int*)d_in[2];
    const int*   edge_type = (const int*)d_in[3];
    const float* Hmat      = (const float*)d_in[4];
    const int*   ro_ids    = (const int*)d_in[5];
    const float* W0        = (const float*)d_in[6];
    const float* W1        = (const float*)d_in[7];
    const float* node_emb  = (const float*)d_in[8];
    const float* a_src     = (const float*)d_in[9];
    const float* a_dst     = (const float*)d_in[10];
    const float* a_edge    = (const float*)d_in[11];
    const float* edge_bias = (const float*)d_in[12];
    const float* node_g    = (const float*)d_in[13];
    const float* node_b    = (const float*)d_in[14];
    const float* bag_g     = (const float*)d_in[15];
    const float* bag_b     = (const float*)d_in[16];

    // Workspace layout (~31 MB). Aliases:
    //   macc = hX slot (dead otherwise), hXb = Xb0 (dead after layer-0 phaseA)
    char* ws = (char*)d_ws;
    size_t off = 0;
    unsigned char* HTb = (unsigned char*)(ws + off); off += (size_t)N_EDGES * NTB;
    unsigned char* HNb = (unsigned char*)(ws + off); off += (size_t)N_TOT * NEB;
    off = (off + 255) & ~(size_t)255;
    float* hP   = (float*)(ws + off); off += (size_t)N_TOT * GNN_DIM * 4;
    float* macc = (float*)(ws + off); off += (size_t)NCHUNK * 1024 * GNN_DIM * 4;  // 8.39 MB
    __hip_bfloat16* hPb = (__hip_bfloat16*)(ws + off); off += (size_t)N_TOT * GNN_DIM * 2;
    __hip_bfloat16* mb  = (__hip_bfloat16*)(ws + off); off += (size_t)N_EDGES * GNN_DIM * 2;
    __hip_bfloat16* Xb0 = (__hip_bfloat16*)(ws + off); off += (size_t)N_TOT * IN_DIM * 2;
    __hip_bfloat16* Wt0 = (__hip_bfloat16*)(ws + off); off += (size_t)GNN_DIM * IN_DIM * 2;
    __hip_bfloat16* Wt1 = (__hip_bfloat16*)(ws + off); off += (size_t)GNN_DIM * GNN_DIM * 2;
    float* expL = (float*)(ws + off); off += (size_t)N_TOT * 12 * 4;
    float* sdst = (float*)(ws + off); off += (size_t)N_TOT * HEADS * 4;
    float* sedg = (float*)(ws + off); off += (size_t)N_EDGES * HEADS * 4;
    float* Zacc = (float*)(ws + off); off += (size_t)NCHUNK * 1024 * HEADS * 4;
    int* outrow = (int*)(ws + off); off += N_TILES * 4;
    __hip_bfloat16* hXb = Xb0;               // alias

    // ----- fused prep -----
    prep1<<<9001, 256, 0, stream>>>(Hmat, HTb, HNb, W0, Wt0, W1, Wt1,
                                    x_nodes, readout, Xb0, ro_ids, outrow);

    // ----- layer 0 -----
    phaseA_mfma<<<N_TOT / 16, 256, 0, stream>>>(Xb0, Wt0, IN_DIM, IN_DIM + 8,
                                      node_emb, node_type,
                                      a_src, a_dst, edge_bias,
                                      hP, hPb, expL, sdst);
    phaseC_acc<<<NCHUNK * 1024, 128, 0, stream>>>(HTb, edge_type, expL, hPb, macc, Zacc);
    phaseC_red<<<N_EDGES, 256, 0, stream>>>(macc, Zacc, a_edge, mb, sedg);
    phaseE<<<N_TOT, 256, 0, stream>>>(HNb, sdst, sedg, mb, hP, hXb);

    // ----- layer 1 -----
    phaseA_mfma<<<N_TOT / 16, 256, 0, stream>>>(hXb, Wt1, GNN_DIM, GNN_DIM + 8,
                                      node_emb + 4 * GNN_DIM, node_type,
                                      a_src + HEADS * DH, a_dst + HEADS * DH,
                                      edge_bias + 12,
                                      hP, hPb, expL, sdst);
    phaseC_acc<<<NCHUNK * 1024, 128, 0, stream>>>(HTb, edge_type, expL, hPb, macc, Zacc);
    phaseC_red<<<N_EDGES, 256, 0, stream>>>(macc, Zacc, a_edge + HEADS * DH, mb, sedg);
    phaseE_last<<<N_TOT, 256, 0, stream>>>(HNb, sdst, sedg, mb, hP,
                                           node_g, node_b, bag_g, bag_b, outrow,
                                           (float*)d_out);
}